// Round 7
// baseline (169.279 us; speedup 1.0000x reference)
//
#include <hip/hip_runtime.h>
#include <hip/hip_bf16.h>
#include <math.h>

#define B_ 2
#define S_ 2048
#define D_ 1024
#define H_ 16
#define HD_ 64
#define R_ 128
#define NBLK 32
#define TOPK_ 4
#define BS_ (B_*S_)

typedef __attribute__((ext_vector_type(8))) short bf16x8;
typedef __attribute__((ext_vector_type(4))) float f32x4;

__device__ __forceinline__ unsigned short f2bf(float f) {
    unsigned int u = __float_as_uint(f);
    u += 0x7fffu + ((u >> 16) & 1u);
    return (unsigned short)(u >> 16);
}
__device__ __forceinline__ float bf2f(unsigned short h) {
    return __uint_as_float(((unsigned int)h) << 16);
}
__device__ __forceinline__ unsigned int pack2(float a, float b) {
    return (unsigned int)f2bf(a) | ((unsigned int)f2bf(b) << 16);
}
__device__ __forceinline__ void gload_lds16(const void* g, void* l) {
    __builtin_amdgcn_global_load_lds((const __attribute__((address_space(1))) void*)g,
                                     (__attribute__((address_space(3))) void*)l, 16, 0, 0);
}

// ---------------- RoPE tables ----------------
__global__ void rope_tables_k(float* __restrict__ cosT, float* __restrict__ sinT) {
    int idx = blockIdx.x*256 + threadIdx.x;
    if (idx >= S_*HD_) return;
    int s  = idx >> 6;
    int hd = idx & 63;
    int j = (hd < 32) ? hd : hd - 32;
    float inv = powf(100000.0f, -((float)(2*j) / 64.0f));
    float fr = (float)s * inv;
    cosT[idx] = cosf(fr);
    sinT[idx] = sinf(fr);
}

// ---------------- segmented weight cvt: w_q|w_kvd -> wcat, w_kvu -> wkub, w_o -> wob ----------------
__global__ __launch_bounds__(256) void cvtw_k(const float* __restrict__ wq,
        const float* __restrict__ wkd, const float* __restrict__ wku,
        const float* __restrict__ wo, unsigned short* __restrict__ wcat,
        unsigned short* __restrict__ wkub, unsigned short* __restrict__ wob) {
    const int blk = blockIdx.x;
    const float* src; unsigned short* dst; int base;
    if      (blk < 512) { src = wq;  dst = wcat;            base = blk;       }
    else if (blk < 576) { src = wkd; dst = wcat + 1048576;  base = blk - 512; }
    else if (blk < 704) { src = wku; dst = wkub;            base = blk - 576; }
    else                { src = wo;  dst = wob;             base = blk - 704; }
    const int i = base*2048 + threadIdx.x*8;
    float4 a = *(const float4*)&src[i];
    float4 b = *(const float4*)&src[i+4];
    uint4 o;
    o.x = pack2(a.x, a.y); o.y = pack2(a.z, a.w);
    o.z = pack2(b.x, b.y); o.w = pack2(b.z, b.w);
    *(uint4*)&dst[i] = o;
}

// ---------------- MFMA GEMM C = A @ B^T, 128x64 tile, BK=64, fused epilogues ----------------
// EPI 0: plain fp32 out (o0).
// EPI 1: cols<1024 -> RoPE -> qrb(o0), else latb(o1).
// EPI 2: cols<1024 -> RoPE -> krb(o0), else V -> transposed vtb(o1) + vsum atomics.
template<int EPI>
__global__ __launch_bounds__(256) void gemm_mfma_k(const unsigned short* __restrict__ A,
        const unsigned short* __restrict__ Bm, int M, int N, int K,
        void* __restrict__ o0, void* __restrict__ o1,
        const float* __restrict__ cosT, const float* __restrict__ sinT,
        float* __restrict__ vsum) {
    __shared__ unsigned short shbuf[128*64 + 64*64];
    unsigned short* As = shbuf;             // [16 chunks][512]
    unsigned short* Bs = shbuf + 128*64;
    const int tid  = threadIdx.x;
    const int wave = tid >> 6, lane = tid & 63;
    const int bm = blockIdx.y << 7, bn = blockIdx.x << 6;
    const int g  = lane >> 4, qc = lane & 15;
    const int srow  = lane >> 3;             // row within 8-row chunk
    const int sslot = (lane & 7) ^ srow;     // inverse-swizzled global 16B slot

    f32x4 acc[2][4];
    #pragma unroll
    for (int m=0;m<2;m++)
        #pragma unroll
        for (int n=0;n<4;n++)
            acc[m][n] = (f32x4){0.f,0.f,0.f,0.f};

    for (int k0 = 0; k0 < K; k0 += 64) {
        __syncthreads();
        #pragma unroll
        for (int it = 0; it < 4; ++it) {
            const int chunk = (it << 2) | wave;       // 0..15
            const int row   = (chunk << 3) | srow;    // 0..127
            gload_lds16(A + (size_t)(bm + row) * K + k0 + (sslot << 3), &As[chunk << 9]);
        }
        #pragma unroll
        for (int it = 0; it < 2; ++it) {
            const int chunk = (it << 2) | wave;       // 0..7
            const int row   = (chunk << 3) | srow;    // 0..63
            gload_lds16(Bm + (size_t)(bn + row) * K + k0 + (sslot << 3), &Bs[chunk << 9]);
        }
        __syncthreads();
        #pragma unroll
        for (int ks = 0; ks < 2; ++ks) {
            const int swb = ((ks << 2) | g) ^ (lane & 7);  // swizzled read slot
            bf16x8 af[2], bfr[4];
            #pragma unroll
            for (int m = 0; m < 2; ++m)
                af[m]  = *(const bf16x8*)&As[(((wave << 5) + (m << 4) + qc) << 6) + (swb << 3)];
            #pragma unroll
            for (int n = 0; n < 4; ++n)
                bfr[n] = *(const bf16x8*)&Bs[(((n << 4) + qc) << 6) + (swb << 3)];
            #pragma unroll
            for (int m = 0; m < 2; ++m)
                #pragma unroll
                for (int n = 0; n < 4; ++n)
                    acc[m][n] = __builtin_amdgcn_mfma_f32_16x16x32_bf16(af[m], bfr[n], acc[m][n], 0, 0, 0);
        }
    }

    if (EPI == 0) {
        float* C = (float*)o0;
        #pragma unroll
        for (int m = 0; m < 2; ++m) {
            const int r0 = bm + (wave << 5) + (m << 4) + (g << 2);
            #pragma unroll
            for (int n = 0; n < 4; ++n) {
                const int c = bn + (n << 4) + qc;
                #pragma unroll
                for (int j = 0; j < 4; ++j)
                    C[(size_t)(r0 + j) * N + c] = acc[m][n][j];
            }
        }
    } else {
        const bool isrope = (bn < 1024);
        if (isrope) {
            const int h = bn >> 6;
            unsigned short* dst = (unsigned short*)o0;   // qrb or krb [B,H,S,HD]
            #pragma unroll
            for (int m = 0; m < 2; ++m) {
                const int r0 = bm + (wave << 5) + (m << 4) + (g << 2);
                #pragma unroll
                for (int j = 0; j < 4; ++j) {
                    const int row = r0 + j;
                    const int b = row >> 11, s = row & (S_-1);
                    const size_t obase = ((size_t)(b*H_ + h) * S_ + s) << 6;
                    #pragma unroll
                    for (int n = 0; n < 4; ++n) {
                        const int hd = (n << 4) + qc;
                        const float c_ = cosT[(s << 6) + hd];
                        const float sn = sinT[(s << 6) + hd];
                        const float rot = (n < 2) ? -acc[m][n ^ 2][j] : acc[m][n ^ 2][j];
                        dst[obase + hd] = f2bf(acc[m][n][j] * c_ + rot * sn);
                    }
                }
            }
        } else if (EPI == 1) {         // latent columns 1024..1151
            unsigned short* latb = (unsigned short*)o1;
            const int c0 = bn - 1024;
            #pragma unroll
            for (int m = 0; m < 2; ++m) {
                const int r0 = bm + (wave << 5) + (m << 4) + (g << 2);
                #pragma unroll
                for (int n = 0; n < 4; ++n) {
                    const int c = c0 + (n << 4) + qc;
                    #pragma unroll
                    for (int j = 0; j < 4; ++j)
                        latb[(size_t)(r0 + j) * R_ + c] = f2bf(acc[m][n][j]);
                }
            }
        } else {   // EPI==2 v-cols: transpose 128x64 tile in LDS -> vtb[bh,kb][d][k], vsum atomics
            const int h  = (bn >> 6) - 16;
            const int b  = bm >> 11, s0 = bm & (S_-1);
            const int bh = (b << 4) + h;
            unsigned short* vtb = (unsigned short*)o1;
            unsigned short (*T)[72] = (unsigned short(*)[72])shbuf;   // [128][72] = 18.4 KB
            __syncthreads();   // all waves done reading As/Bs
            #pragma unroll
            for (int m = 0; m < 2; ++m) {
                const int r0 = (wave << 5) + (m << 4) + (g << 2);
                #pragma unroll
                for (int n = 0; n < 4; ++n)
                    #pragma unroll
                    for (int j = 0; j < 4; ++j)
                        T[r0 + j][(n << 4) + qc] = f2bf(acc[m][n][j]);
            }
            __syncthreads();
            #pragma unroll
            for (int u = 0; u < 2; ++u) {            // two 64-key halves
                const int kb = (s0 >> 6) + u;
                unsigned short* dst = vtb + (((size_t)(bh * NBLK + kb)) << 12);
                #pragma unroll
                for (int uu = 0; uu < 2; ++uu) {
                    const int idx = (uu << 8) + tid;     // 0..511
                    const int dd = idx >> 3, k0 = (idx & 7) << 3;
                    unsigned short tmp[8];
                    float sm = 0.f;
                    #pragma unroll
                    for (int j = 0; j < 8; ++j) { tmp[j] = T[(u << 6) + k0 + j][dd]; sm += bf2f(tmp[j]); }
                    *(uint4*)&dst[(size_t)(dd << 6) + k0] = *(uint4*)tmp;
                    sm += __shfl_xor(sm, 1);
                    sm += __shfl_xor(sm, 2);
                    sm += __shfl_xor(sm, 4);
                    if ((tid & 7) == 0) atomicAdd(&vsum[(bh << 6) + dd], sm);
                }
            }
        }
    }
}

// ---------------- row scores + x->bf16: one wave per 4 rows ----------------
__global__ __launch_bounds__(256) void rowscore_cvt_k(const float* __restrict__ x,
        const float* __restrict__ wsc, float* __restrict__ rows,
        unsigned short* __restrict__ xb) {
    const int wid  = (blockIdx.x << 2) + (threadIdx.x >> 6);  // 0..1023
    const int lane = threadIdx.x & 63;
    #pragma unroll
    for (int r = 0; r < 4; ++r) {
        const int row = (wid << 2) + r;                        // 0..4095
        const float* xp = x + (size_t)row * D_;
        unsigned short* xo = xb + (size_t)row * D_;
        float acc = 0.f;
        #pragma unroll
        for (int j = 0; j < 4; ++j) {
            const int off = ((j << 6) + lane) << 2;            // coalesced float4
            float4 xv = *(const float4*)&xp[off];
            float4 wv = *(const float4*)&wsc[off];
            acc = fmaf(xv.x, wv.x, acc);
            acc = fmaf(xv.y, wv.y, acc);
            acc = fmaf(xv.z, wv.z, acc);
            acc = fmaf(xv.w, wv.w, acc);
            uint2 o; o.x = pack2(xv.x, xv.y); o.y = pack2(xv.z, xv.w);
            *(uint2*)&xo[off] = o;
        }
        #pragma unroll
        for (int m = 1; m <= 32; m <<= 1) acc += __shfl_xor(acc, m);
        if (lane == 0) rows[row] = acc;
    }
}

// ---------------- block sums + top-4 (strict > == lowest index on ties) ----------------
__global__ __launch_bounds__(256) void blocktopk_k(const float* __restrict__ rows,
        int* __restrict__ sel) {
    __shared__ float bs[64];
    const int bk = threadIdx.x >> 2, qt = threadIdx.x & 3;     // block 0..63, quarter
    const float* rp = rows + (bk << 6) + (qt << 4);
    float p = 0.f;
    #pragma unroll
    for (int i = 0; i < 16; ++i) p += rp[i];
    p += __shfl_xor(p, 1);
    p += __shfl_xor(p, 2);
    if (qt == 0) bs[bk] = p;
    __syncthreads();
    if (threadIdx.x < B_) {
        const int b = threadIdx.x;
        float sc[NBLK];
        for (int i = 0; i < NBLK; ++i) sc[i] = bs[b * NBLK + i];
        for (int j = 0; j < TOPK_; ++j) {
            float best = -INFINITY; int bi = 0;
            for (int i = 0; i < NBLK; ++i)
                if (sc[i] > best) { best = sc[i]; bi = i; }
            sel[b * TOPK_ + j] = bi;
            sc[bi] = -INFINITY;
        }
    }
}

// ---------------- MFMA block-sparse attention, barrier-free: K/Vt frags direct from L2 ----------------
__global__ __launch_bounds__(256) void attn_mfma_k(const unsigned short* __restrict__ qrb,
        const unsigned short* __restrict__ krb, const unsigned short* __restrict__ vtb,
        const int* __restrict__ sel, const float* __restrict__ vsum,
        unsigned short* __restrict__ attno) {
    const int qb = blockIdx.x & (NBLK-1);
    const int bh = blockIdx.x >> 5;
    const int b  = bh >> 4;
    const int h  = bh & 15;
    const int tid  = threadIdx.x;
    const int wave = tid >> 6, lane = tid & 63;
    const int g = lane >> 4, qc = lane & 15;

    __shared__ unsigned short Pl[4][16][72];   // per-wave P [q][key]
    __shared__ float cfl[4][16];
    __shared__ float lvl[4][16];

    int selb[4];
    #pragma unroll
    for (int j=0;j<4;j++) selb[j] = sel[(b<<2)+j];
    const bool diag = (selb[0]==qb)|(selb[1]==qb)|(selb[2]==qb)|(selb[3]==qb);

    // Q B-frags (per wave: rows qb*64 + wave*16 .. +16)
    const unsigned short* qp = qrb + (((size_t)bh*S_ + (qb<<6) + (wave<<4) + qc) << 6);
    bf16x8 bq[2];
    bq[0] = *(const bf16x8*)(qp + (g<<3));
    bq[1] = *(const bf16x8*)(qp + 32 + (g<<3));

    f32x4 oacc[4];
    #pragma unroll
    for (int n=0;n<4;n++) oacc[n] = (f32x4){0.f,0.f,0.f,0.f};
    float mrun = -INFINITY, lrun = 0.f;
    int nproc = 0;
    const int qib = (wave<<4) + qc;   // this lane's q-row within the 64-block

    for (int j = 0; j < 5; ++j) {     // wg-uniform control flow
        int kb; bool isdiag;
        if (j < 4) { kb = selb[j]; isdiag = false; if (kb >= qb) continue; }
        else       { if (!diag) continue; kb = qb; isdiag = true; }
        nproc++;
        const unsigned short* kB = krb + (((size_t)bh*S_ + (kb<<6)) << 6);
        const unsigned short* vT = vtb + (((size_t)(bh*NBLK + kb)) << 12);

        // load K A-frags and Vt B-frags straight into registers (L2-served)
        bf16x8 ak[2][4], vb[2][4];
        #pragma unroll
        for (int ks=0;ks<2;ks++)
            #pragma unroll
            for (int m=0;m<4;m++)
                ak[ks][m] = *(const bf16x8*)(kB + (((m<<4)+qc)<<6) + (ks<<5) + (g<<3));
        #pragma unroll
        for (int ks=0;ks<2;ks++)
            #pragma unroll
            for (int n=0;n<4;n++)
                vb[ks][n] = *(const bf16x8*)(vT + (((n<<4)+qc)<<6) + (ks<<5) + (g<<3));

        // S^T = K @ Q^T : lane holds q-col=qc, keys 16m+4g+{0..3}
        f32x4 sf[4];
        #pragma unroll
        for (int m=0;m<4;m++) sf[m] = (f32x4){0.f,0.f,0.f,0.f};
        #pragma unroll
        for (int ks=0;ks<2;ks++)
            #pragma unroll
            for (int m=0;m<4;m++)
                sf[m] = __builtin_amdgcn_mfma_f32_16x16x32_bf16(ak[ks][m], bq[ks], sf[m], 0, 0, 0);

        float s[16];
        float bmax = -INFINITY;
        #pragma unroll
        for (int m=0;m<4;m++)
            #pragma unroll
            for (int r2=0;r2<4;r2++) {
                const int kl = (m<<4)+(g<<2)+r2;
                float v = sf[m][r2]*0.125f;
                if (isdiag && kl > qib) v = -1e30f;
                s[(m<<2)+r2] = v;
                bmax = fmaxf(bmax, v);
            }
        bmax = fmaxf(bmax, __shfl_xor(bmax, 16));
        bmax = fmaxf(bmax, __shfl_xor(bmax, 32));
        const float mnew = fmaxf(mrun, bmax);
        const float cf = __expf(mrun - mnew);
        float ls = 0.f;
        #pragma unroll
        for (int m=0;m<4;m++) {
            float p0 = __expf(s[(m<<2)+0]-mnew);
            float p1 = __expf(s[(m<<2)+1]-mnew);
            float p2 = __expf(s[(m<<2)+2]-mnew);
            float p3 = __expf(s[(m<<2)+3]-mnew);
            ls += p0+p1+p2+p3;
            const int koff = (m<<4)+(g<<2);
            *(unsigned int*)&Pl[wave][qc][koff]   = pack2(p0,p1);
            *(unsigned int*)&Pl[wave][qc][koff+2] = pack2(p2,p3);
        }
        ls += __shfl_xor(ls, 16);
        ls += __shfl_xor(ls, 32);
        lrun = lrun*cf + ls;
        cfl[wave][qc] = cf;
        // rescale O rows (lane's O-rows are 4g+r2 -> need those rows' cf)
        f32x4 cf4 = *(const f32x4*)&cfl[wave][g<<2];
        #pragma unroll
        for (int n=0;n<4;n++) oacc[n] *= cf4;
        // O += P @ V  (A = P from per-wave LDS, B = Vt frags in regs)
        #pragma unroll
        for (int ks=0;ks<2;ks++) {
            bf16x8 pa = *(const bf16x8*)&Pl[wave][qc][(ks<<5)+(g<<3)];
            #pragma unroll
            for (int n=0;n<4;n++)
                oacc[n] = __builtin_amdgcn_mfma_f32_16x16x32_bf16(pa, vb[ks][n], oacc[n], 0, 0, 0);
        }
        mrun = mnew;
    }

    f32x4 il4 = (f32x4){0.f,0.f,0.f,0.f};
    if (nproc) {
        lvl[wave][qc] = 1.0f / lrun;
        il4 = *(const f32x4*)&lvl[wave][g<<2];
    }
    #pragma unroll
    for (int n=0;n<4;n++)
        #pragma unroll
        for (int r2=0;r2<4;r2++) {
            float val = nproc ? oacc[n][r2]*il4[r2]
                              : vsum[(bh<<6)+(n<<4)+qc] * (1.0f/(float)S_);
            const int row = (qb<<6) + (wave<<4) + (g<<2) + r2;
            attno[(((size_t)(b*S_+row))<<10) + (h<<6) + (n<<4) + qc] = f2bf(val);
        }
}

extern "C" void kernel_launch(void* const* d_in, const int* in_sizes, int n_in,
                              void* d_out, int out_size, void* d_ws, size_t ws_size,
                              hipStream_t stream) {
    (void)in_sizes; (void)n_in; (void)out_size; (void)ws_size;
    const float* x     = (const float*)d_in[0];
    const float* w_q   = (const float*)d_in[1];
    const float* w_kvd = (const float*)d_in[2];
    const float* w_kvu = (const float*)d_in[3];
    const float* w_o   = (const float*)d_in[4];
    const float* w_sc  = (const float*)d_in[5];
    float* out = (float*)d_out;

    char* p = (char*)d_ws;
    auto alloc = [&](size_t bytes) -> void* {
        void* r = (void*)p;
        p += (bytes + 255) & ~(size_t)255;
        return r;
    };
    float* cosT  = (float*)alloc((size_t)S_*HD_*4);
    float* sinT  = (float*)alloc((size_t)S_*HD_*4);
    unsigned short* xb    = (unsigned short*)alloc((size_t)BS_*D_*2);
    unsigned short* wcat  = (unsigned short*)alloc((size_t)(D_+R_)*D_*2);   // w_q ; w_kvd
    unsigned short* wkub  = (unsigned short*)alloc((size_t)2*D_*R_*2);
    unsigned short* wob   = (unsigned short*)alloc((size_t)D_*D_*2);
    unsigned short* latb  = (unsigned short*)alloc((size_t)BS_*R_*2);
    unsigned short* qrb   = (unsigned short*)alloc((size_t)BS_*D_*2);
    unsigned short* krb   = (unsigned short*)alloc((size_t)BS_*D_*2);
    unsigned short* vtb   = (unsigned short*)alloc((size_t)BS_*D_*2);
    unsigned short* attnob= (unsigned short*)alloc((size_t)BS_*D_*2);
    float* rows   = (float*)alloc((size_t)BS_*4);
    int*   sel    = (int*)  alloc((size_t)B_*TOPK_*4);
    float* vsum   = (float*)alloc((size_t)B_*H_*HD_*4);

    rope_tables_k<<<(S_*HD_+255)/256, 256, 0, stream>>>(cosT, sinT);
    cvtw_k<<<1216, 256, 0, stream>>>(w_q, w_kvd, w_kvu, w_o, wcat, wkub, wob);
    rowscore_cvt_k<<<256, 256, 0, stream>>>(x, w_sc, rows, xb);
    blocktopk_k<<<1, 256, 0, stream>>>(rows, sel);

    // q-proj + kv-down fused (N = 1024 + 128), RoPE'd q -> qrb, latent -> latb
    gemm_mfma_k<1><<<dim3((D_+R_)/64, BS_/128), 256, 0, stream>>>(
        xb, wcat, BS_, D_+R_, D_, qrb, latb, cosT, sinT, nullptr);
    hipMemsetAsync(vsum, 0, (size_t)B_*H_*HD_*4, stream);
    // kv-up: RoPE'd k -> krb, v -> transposed vtb (+vsum)
    gemm_mfma_k<2><<<dim3(2*D_/64, BS_/128), 256, 0, stream>>>(
        latb, wkub, BS_, 2*D_, R_, krb, vtb, cosT, sinT, vsum);

    attn_mfma_k<<<B_*H_*NBLK, 256, 0, stream>>>(qrb, krb, vtb, sel, vsum, attnob);
    gemm_mfma_k<0><<<dim3(D_/64, BS_/128), 256, 0, stream>>>(
        attnob, wob, BS_, D_, D_, out, nullptr, nullptr, nullptr, nullptr);
}

// Round 8
// 152.640 us; speedup vs baseline: 1.1090x; 1.1090x over previous
//
#include <hip/hip_runtime.h>
#include <hip/hip_bf16.h>
#include <math.h>

#define B_ 2
#define S_ 2048
#define D_ 1024
#define H_ 16
#define HD_ 64
#define R_ 128
#define NBLK 32
#define TOPK_ 4
#define BS_ (B_*S_)

typedef __attribute__((ext_vector_type(8))) short bf16x8;
typedef __attribute__((ext_vector_type(4))) float f32x4;

__device__ __forceinline__ unsigned short f2bf(float f) {
    unsigned int u = __float_as_uint(f);
    u += 0x7fffu + ((u >> 16) & 1u);
    return (unsigned short)(u >> 16);
}
__device__ __forceinline__ float bf2f(unsigned short h) {
    return __uint_as_float(((unsigned int)h) << 16);
}
__device__ __forceinline__ unsigned int pack2(float a, float b) {
    return (unsigned int)f2bf(a) | ((unsigned int)f2bf(b) << 16);
}
__device__ __forceinline__ void gload_lds16(const void* g, void* l) {
    __builtin_amdgcn_global_load_lds((const __attribute__((address_space(1))) void*)g,
                                     (__attribute__((address_space(3))) void*)l, 16, 0, 0);
}

// ---------------- RoPE tables ----------------
__global__ void rope_tables_k(float* __restrict__ cosT, float* __restrict__ sinT) {
    int idx = blockIdx.x*256 + threadIdx.x;
    if (idx >= S_*HD_) return;
    int s  = idx >> 6;
    int hd = idx & 63;
    int j = (hd < 32) ? hd : hd - 32;
    float inv = powf(100000.0f, -((float)(2*j) / 64.0f));
    float fr = (float)s * inv;
    cosT[idx] = cosf(fr);
    sinT[idx] = sinf(fr);
}

// ---------------- segmented weight cvt: w_q|w_kvd -> wcat, w_kvu -> wkub, w_o -> wob ----------------
__global__ __launch_bounds__(256) void cvtw_k(const float* __restrict__ wq,
        const float* __restrict__ wkd, const float* __restrict__ wku,
        const float* __restrict__ wo, unsigned short* __restrict__ wcat,
        unsigned short* __restrict__ wkub, unsigned short* __restrict__ wob) {
    const int blk = blockIdx.x;
    const float* src; unsigned short* dst; int base;
    if      (blk < 512) { src = wq;  dst = wcat;            base = blk;       }
    else if (blk < 576) { src = wkd; dst = wcat + 1048576;  base = blk - 512; }
    else if (blk < 704) { src = wku; dst = wkub;            base = blk - 576; }
    else                { src = wo;  dst = wob;             base = blk - 704; }
    const int i = base*2048 + threadIdx.x*8;
    float4 a = *(const float4*)&src[i];
    float4 b = *(const float4*)&src[i+4];
    uint4 o;
    o.x = pack2(a.x, a.y); o.y = pack2(a.z, a.w);
    o.z = pack2(b.x, b.y); o.w = pack2(b.z, b.w);
    *(uint4*)&dst[i] = o;
}

// ---------------- MFMA GEMM C = A @ B^T, 128x64 tile, BK=64, 2-phase dbuf pipeline ----------------
// 1D grid (nwg % 8 == 0), XCD-aware swizzle. EPI 0: fp32 out (o0).
// EPI 1: cols<1024 -> RoPE -> qrb(o0), else latb(o1).
// EPI 2: cols<1024 -> RoPE -> krb(o0), else V -> transposed vtb(o1) + vsum atomics.
template<int EPI>
__global__ __launch_bounds__(256) void gemm_mfma_k(const unsigned short* __restrict__ A,
        const unsigned short* __restrict__ Bm, int M, int N, int K,
        void* __restrict__ o0, void* __restrict__ o1,
        const float* __restrict__ cosT, const float* __restrict__ sinT,
        float* __restrict__ vsum) {
    __shared__ unsigned short shbuf[2][12288];   // per buf: As[8192] | Bs[4096]  (48 KB)
    const int tid  = threadIdx.x;
    const int wave = tid >> 6, lane = tid & 63;
    // XCD swizzle: contiguous per-XCD chunks walk (m,n) row-major -> A-panel reuse in XCD L2
    const int nx = N >> 6;
    const int ob = blockIdx.x;
    const int w  = ((ob & 7) * (gridDim.x >> 3)) + (ob >> 3);
    const int bm = (w / nx) << 7, bn = (w % nx) << 6;
    const int g  = lane >> 4, qc = lane & 15;
    const int srow  = lane >> 3;             // row within 8-row chunk
    const int sslot = (lane & 7) ^ srow;     // inverse-swizzled global 16B slot

    f32x4 acc[2][4];
    #pragma unroll
    for (int m=0;m<2;m++)
        #pragma unroll
        for (int n=0;n<4;n++)
            acc[m][n] = (f32x4){0.f,0.f,0.f,0.f};

    const int NT = K >> 6;
    auto STAGE = [&](int buf, int t) {
        const int k0 = t << 6;
        unsigned short* As = shbuf[buf];
        unsigned short* Bs = shbuf[buf] + 8192;
        #pragma unroll
        for (int it = 0; it < 4; ++it) {
            const int chunk = (it << 2) | wave;       // 0..15
            const int row   = (chunk << 3) | srow;    // 0..127
            gload_lds16(A + (size_t)(bm + row) * K + k0 + (sslot << 3), &As[chunk << 9]);
        }
        #pragma unroll
        for (int it = 0; it < 2; ++it) {
            const int chunk = (it << 2) | wave;       // 0..7
            const int row   = (chunk << 3) | srow;    // 0..63
            gload_lds16(Bm + (size_t)(bn + row) * K + k0 + (sslot << 3), &Bs[chunk << 9]);
        }
    };

    STAGE(0, 0);
    __syncthreads();                                  // drain prologue
    for (int t = 0; t < NT; ++t) {
        if (t + 1 < NT) STAGE((t + 1) & 1, t + 1);    // loads fly under compute
        const unsigned short* As = shbuf[t & 1];
        const unsigned short* Bs = shbuf[t & 1] + 8192;
        #pragma unroll
        for (int ks = 0; ks < 2; ++ks) {
            const int swb = ((ks << 2) | g) ^ (lane & 7);  // swizzled read slot
            bf16x8 af[2], bfr[4];
            #pragma unroll
            for (int m = 0; m < 2; ++m)
                af[m]  = *(const bf16x8*)&As[(((wave << 5) + (m << 4) + qc) << 6) + (swb << 3)];
            #pragma unroll
            for (int n = 0; n < 4; ++n)
                bfr[n] = *(const bf16x8*)&Bs[(((n << 4) + qc) << 6) + (swb << 3)];
            #pragma unroll
            for (int m = 0; m < 2; ++m)
                #pragma unroll
                for (int n = 0; n < 4; ++n)
                    acc[m][n] = __builtin_amdgcn_mfma_f32_16x16x32_bf16(af[m], bfr[n], acc[m][n], 0, 0, 0);
        }
        __syncthreads();                              // vmcnt(0)+barrier: next tile ready
    }

    if (EPI == 0) {
        float* C = (float*)o0;
        #pragma unroll
        for (int m = 0; m < 2; ++m) {
            const int r0 = bm + (wave << 5) + (m << 4) + (g << 2);
            #pragma unroll
            for (int n = 0; n < 4; ++n) {
                const int c = bn + (n << 4) + qc;
                #pragma unroll
                for (int j = 0; j < 4; ++j)
                    C[(size_t)(r0 + j) * N + c] = acc[m][n][j];
            }
        }
    } else {
        const bool isrope = (bn < 1024);
        if (isrope) {
            const int h = bn >> 6;
            unsigned short* dst = (unsigned short*)o0;   // qrb or krb [B,H,S,HD]
            #pragma unroll
            for (int m = 0; m < 2; ++m) {
                const int r0 = bm + (wave << 5) + (m << 4) + (g << 2);
                #pragma unroll
                for (int j = 0; j < 4; ++j) {
                    const int row = r0 + j;
                    const int b = row >> 11, s = row & (S_-1);
                    const size_t obase = ((size_t)(b*H_ + h) * S_ + s) << 6;
                    #pragma unroll
                    for (int n = 0; n < 4; ++n) {
                        const int hd = (n << 4) + qc;
                        const float c_ = cosT[(s << 6) + hd];
                        const float sn = sinT[(s << 6) + hd];
                        const float rot = (n < 2) ? -acc[m][n ^ 2][j] : acc[m][n ^ 2][j];
                        dst[obase + hd] = f2bf(acc[m][n][j] * c_ + rot * sn);
                    }
                }
            }
        } else if (EPI == 1) {         // latent columns 1024..1151
            unsigned short* latb = (unsigned short*)o1;
            const int c0 = bn - 1024;
            #pragma unroll
            for (int m = 0; m < 2; ++m) {
                const int r0 = bm + (wave << 5) + (m << 4) + (g << 2);
                #pragma unroll
                for (int n = 0; n < 4; ++n) {
                    const int c = c0 + (n << 4) + qc;
                    #pragma unroll
                    for (int j = 0; j < 4; ++j)
                        latb[(size_t)(r0 + j) * R_ + c] = f2bf(acc[m][n][j]);
                }
            }
        } else {   // EPI==2 v-cols: LDS-transpose 128x64 tile -> vtb[bh,kb][d][k] + vsum atomics
            const int h  = (bn >> 6) - 16;
            const int b  = bm >> 11, s0 = bm & (S_-1);
            const int bh = (b << 4) + h;
            unsigned short* vtb = (unsigned short*)o1;
            unsigned short (*T)[72] = (unsigned short(*)[72])&shbuf[0][0];   // 18 KB
            #pragma unroll
            for (int m = 0; m < 2; ++m) {
                const int r0 = (wave << 5) + (m << 4) + (g << 2);
                #pragma unroll
                for (int n = 0; n < 4; ++n)
                    #pragma unroll
                    for (int j = 0; j < 4; ++j)
                        T[r0 + j][(n << 4) + qc] = f2bf(acc[m][n][j]);
            }
            __syncthreads();
            #pragma unroll
            for (int u = 0; u < 2; ++u) {            // two 64-key halves
                const int kb = (s0 >> 6) + u;
                unsigned short* dst = vtb + (((size_t)(bh * NBLK + kb)) << 12);
                #pragma unroll
                for (int uu = 0; uu < 2; ++uu) {
                    const int idx = (uu << 8) + tid;     // 0..511
                    const int dd = idx >> 3, k0 = (idx & 7) << 3;
                    unsigned short tmp[8];
                    float sm = 0.f;
                    #pragma unroll
                    for (int j = 0; j < 8; ++j) { tmp[j] = T[(u << 6) + k0 + j][dd]; sm += bf2f(tmp[j]); }
                    *(uint4*)&dst[(size_t)(dd << 6) + k0] = *(uint4*)tmp;
                    sm += __shfl_xor(sm, 1);
                    sm += __shfl_xor(sm, 2);
                    sm += __shfl_xor(sm, 4);
                    if ((tid & 7) == 0) atomicAdd(&vsum[(bh << 6) + dd], sm);
                }
            }
        }
    }
}

// ---------------- row scores + x->bf16: one wave per 4 rows ----------------
__global__ __launch_bounds__(256) void rowscore_cvt_k(const float* __restrict__ x,
        const float* __restrict__ wsc, float* __restrict__ rows,
        unsigned short* __restrict__ xb) {
    const int wid  = (blockIdx.x << 2) + (threadIdx.x >> 6);  // 0..1023
    const int lane = threadIdx.x & 63;
    #pragma unroll
    for (int r = 0; r < 4; ++r) {
        const int row = (wid << 2) + r;                        // 0..4095
        const float* xp = x + (size_t)row * D_;
        unsigned short* xo = xb + (size_t)row * D_;
        float acc = 0.f;
        #pragma unroll
        for (int j = 0; j < 4; ++j) {
            const int off = ((j << 6) + lane) << 2;            // coalesced float4
            float4 xv = *(const float4*)&xp[off];
            float4 wv = *(const float4*)&wsc[off];
            acc = fmaf(xv.x, wv.x, acc);
            acc = fmaf(xv.y, wv.y, acc);
            acc = fmaf(xv.z, wv.z, acc);
            acc = fmaf(xv.w, wv.w, acc);
            uint2 o; o.x = pack2(xv.x, xv.y); o.y = pack2(xv.z, xv.w);
            *(uint2*)&xo[off] = o;
        }
        #pragma unroll
        for (int m = 1; m <= 32; m <<= 1) acc += __shfl_xor(acc, m);
        if (lane == 0) rows[row] = acc;
    }
}

// ---------------- block sums + top-4 (strict > == lowest index on ties) ----------------
__global__ __launch_bounds__(256) void blocktopk_k(const float* __restrict__ rows,
        int* __restrict__ sel) {
    __shared__ float bs[64];
    const int bk = threadIdx.x >> 2, qt = threadIdx.x & 3;     // block 0..63, quarter
    const float* rp = rows + (bk << 6) + (qt << 4);
    float p = 0.f;
    #pragma unroll
    for (int i = 0; i < 16; ++i) p += rp[i];
    p += __shfl_xor(p, 1);
    p += __shfl_xor(p, 2);
    if (qt == 0) bs[bk] = p;
    __syncthreads();
    if (threadIdx.x < B_) {
        const int b = threadIdx.x;
        float sc[NBLK];
        for (int i = 0; i < NBLK; ++i) sc[i] = bs[b * NBLK + i];
        for (int j = 0; j < TOPK_; ++j) {
            float best = -INFINITY; int bi = 0;
            for (int i = 0; i < NBLK; ++i)
                if (sc[i] > best) { best = sc[i]; bi = i; }
            sel[b * TOPK_ + j] = bi;
            sc[bi] = -INFINITY;
        }
    }
}

// ---------------- MFMA block-sparse attention: wg=(b,h,qb), 4 waves x 16 q-rows, LDS-staged ----------------
__global__ __launch_bounds__(256) void attn_mfma_k(const unsigned short* __restrict__ qrb,
        const unsigned short* __restrict__ krb, const unsigned short* __restrict__ vtb,
        const int* __restrict__ sel, const float* __restrict__ vsum,
        unsigned short* __restrict__ attno) {
    const int qb = blockIdx.x & (NBLK-1);
    const int bh = blockIdx.x >> 5;
    const int b  = bh >> 4;
    const int h  = bh & 15;
    const int tid  = threadIdx.x;
    const int wave = tid >> 6, lane = tid & 63;
    const int g = lane >> 4, qc = lane & 15;

    __shared__ unsigned short Ks[64][72];      // [key][d]
    __shared__ unsigned short Vt[64][72];      // [d][key]
    __shared__ unsigned short Pl[4][16][72];   // per-wave P [q][key]
    __shared__ float cfl[4][16];
    __shared__ float lvl[4][16];

    int selb[4];
    #pragma unroll
    for (int j=0;j<4;j++) selb[j] = sel[(b<<2)+j];
    const bool diag = (selb[0]==qb)|(selb[1]==qb)|(selb[2]==qb)|(selb[3]==qb);

    // Q B-frags (per wave: rows qb*64 + wave*16 .. +16)
    const unsigned short* qp = qrb + (((size_t)bh*S_ + (qb<<6) + (wave<<4) + qc) << 6);
    bf16x8 bq[2];
    bq[0] = *(const bf16x8*)(qp + (g<<3));
    bq[1] = *(const bf16x8*)(qp + 32 + (g<<3));

    f32x4 oacc[4];
    #pragma unroll
    for (int n=0;n<4;n++) oacc[n] = (f32x4){0.f,0.f,0.f,0.f};
    float mrun = -INFINITY, lrun = 0.f;
    int nproc = 0;
    const int qib = (wave<<4) + qc;   // this lane's q-row within the 64-block

    for (int j = 0; j < 5; ++j) {     // wg-uniform control flow
        int kb; bool isdiag;
        if (j < 4) { kb = selb[j]; isdiag = false; if (kb >= qb) continue; }
        else       { if (!diag) continue; kb = qb; isdiag = true; }
        nproc++;
        const uint4* gk = (const uint4*)(krb + (((size_t)bh*S_ + (kb<<6)) << 6));
        const uint4* gv = (const uint4*)(vtb + (((size_t)(bh*NBLK + kb)) << 12));
        __syncthreads();
        #pragma unroll
        for (int u=0;u<2;u++) {
            int idx = (u<<8) + tid;      // 0..511
            int r = idx>>3, c = (idx&7)<<3;
            *(uint4*)&Ks[r][c] = gk[idx];
            *(uint4*)&Vt[r][c] = gv[idx];
        }
        __syncthreads();

        // S^T = K @ Q^T : lane holds q-col=qc, keys 16m+4g+{0..3}
        f32x4 sf[4];
        #pragma unroll
        for (int m=0;m<4;m++) sf[m] = (f32x4){0.f,0.f,0.f,0.f};
        #pragma unroll
        for (int ks=0;ks<2;ks++)
            #pragma unroll
            for (int m=0;m<4;m++) {
                bf16x8 ak = *(const bf16x8*)&Ks[(m<<4)+qc][(ks<<5)+(g<<3)];
                sf[m] = __builtin_amdgcn_mfma_f32_16x16x32_bf16(ak, bq[ks], sf[m], 0, 0, 0);
            }

        float s[16];
        float bmax = -INFINITY;
        #pragma unroll
        for (int m=0;m<4;m++)
            #pragma unroll
            for (int r2=0;r2<4;r2++) {
                const int kl = (m<<4)+(g<<2)+r2;
                float v = sf[m][r2]*0.125f;
                if (isdiag && kl > qib) v = -1e30f;
                s[(m<<2)+r2] = v;
                bmax = fmaxf(bmax, v);
            }
        bmax = fmaxf(bmax, __shfl_xor(bmax, 16));
        bmax = fmaxf(bmax, __shfl_xor(bmax, 32));
        const float mnew = fmaxf(mrun, bmax);
        const float cf = __expf(mrun - mnew);
        float ls = 0.f;
        #pragma unroll
        for (int m=0;m<4;m++) {
            float p0 = __expf(s[(m<<2)+0]-mnew);
            float p1 = __expf(s[(m<<2)+1]-mnew);
            float p2 = __expf(s[(m<<2)+2]-mnew);
            float p3 = __expf(s[(m<<2)+3]-mnew);
            ls += p0+p1+p2+p3;
            const int koff = (m<<4)+(g<<2);
            *(unsigned int*)&Pl[wave][qc][koff]   = pack2(p0,p1);
            *(unsigned int*)&Pl[wave][qc][koff+2] = pack2(p2,p3);
        }
        ls += __shfl_xor(ls, 16);
        ls += __shfl_xor(ls, 32);
        lrun = lrun*cf + ls;
        cfl[wave][qc] = cf;
        // rescale O rows (lane's O-rows are 4g+r2 -> need those rows' cf)
        f32x4 cf4 = *(const f32x4*)&cfl[wave][g<<2];
        #pragma unroll
        for (int n=0;n<4;n++) oacc[n] *= cf4;
        // O += P @ V  (A = P from per-wave LDS, B = Vt rows from LDS)
        #pragma unroll
        for (int ks=0;ks<2;ks++) {
            bf16x8 pa = *(const bf16x8*)&Pl[wave][qc][(ks<<5)+(g<<3)];
            #pragma unroll
            for (int n=0;n<4;n++) {
                bf16x8 vb = *(const bf16x8*)&Vt[(n<<4)+qc][(ks<<5)+(g<<3)];
                oacc[n] = __builtin_amdgcn_mfma_f32_16x16x32_bf16(pa, vb, oacc[n], 0, 0, 0);
            }
        }
        mrun = mnew;
    }

    f32x4 il4 = (f32x4){0.f,0.f,0.f,0.f};
    if (nproc) {
        lvl[wave][qc] = 1.0f / lrun;
        il4 = *(const f32x4*)&lvl[wave][g<<2];
    }
    #pragma unroll
    for (int n=0;n<4;n++)
        #pragma unroll
        for (int r2=0;r2<4;r2++) {
            float val = nproc ? oacc[n][r2]*il4[r2]
                              : vsum[(bh<<6)+(n<<4)+qc] * (1.0f/(float)S_);
            const int row = (qb<<6) + (wave<<4) + (g<<2) + r2;
            attno[(((size_t)(b*S_+row))<<10) + (h<<6) + (n<<4) + qc] = f2bf(val);
        }
}

extern "C" void kernel_launch(void* const* d_in, const int* in_sizes, int n_in,
                              void* d_out, int out_size, void* d_ws, size_t ws_size,
                              hipStream_t stream) {
    (void)in_sizes; (void)n_in; (void)out_size; (void)ws_size;
    const float* x     = (const float*)d_in[0];
    const float* w_q   = (const float*)d_in[1];
    const float* w_kvd = (const float*)d_in[2];
    const float* w_kvu = (const float*)d_in[3];
    const float* w_o   = (const float*)d_in[4];
    const float* w_sc  = (const float*)d_in[5];
    float* out = (float*)d_out;

    char* p = (char*)d_ws;
    auto alloc = [&](size_t bytes) -> void* {
        void* r = (void*)p;
        p += (bytes + 255) & ~(size_t)255;
        return r;
    };
    float* cosT  = (float*)alloc((size_t)S_*HD_*4);
    float* sinT  = (float*)alloc((size_t)S_*HD_*4);
    unsigned short* xb    = (unsigned short*)alloc((size_t)BS_*D_*2);
    unsigned short* wcat  = (unsigned short*)alloc((size_t)(D_+R_)*D_*2);   // w_q ; w_kvd
    unsigned short* wkub  = (unsigned short*)alloc((size_t)2*D_*R_*2);
    unsigned short* wob   = (unsigned short*)alloc((size_t)D_*D_*2);
    unsigned short* latb  = (unsigned short*)alloc((size_t)BS_*R_*2);
    unsigned short* qrb   = (unsigned short*)alloc((size_t)BS_*D_*2);
    unsigned short* krb   = (unsigned short*)alloc((size_t)BS_*D_*2);
    unsigned short* vtb   = (unsigned short*)alloc((size_t)BS_*D_*2);
    unsigned short* attnob= (unsigned short*)alloc((size_t)BS_*D_*2);
    float* rows   = (float*)alloc((size_t)BS_*4);
    int*   sel    = (int*)  alloc((size_t)B_*TOPK_*4);
    float* vsum   = (float*)alloc((size_t)B_*H_*HD_*4);

    rope_tables_k<<<(S_*HD_+255)/256, 256, 0, stream>>>(cosT, sinT);
    cvtw_k<<<1216, 256, 0, stream>>>(w_q, w_kvd, w_kvu, w_o, wcat, wkub, wob);
    rowscore_cvt_k<<<256, 256, 0, stream>>>(x, w_sc, rows, xb);
    blocktopk_k<<<1, 256, 0, stream>>>(rows, sel);

    // q-proj + kv-down fused (N = 1024 + 128), RoPE'd q -> qrb, latent -> latb
    gemm_mfma_k<1><<<576, 256, 0, stream>>>(
        xb, wcat, BS_, D_+R_, D_, qrb, latb, cosT, sinT, nullptr);
    hipMemsetAsync(vsum, 0, (size_t)B_*H_*HD_*4, stream);
    // kv-up: RoPE'd k -> krb, v -> transposed vtb (+vsum)
    gemm_mfma_k<2><<<1024, 256, 0, stream>>>(
        latb, wkub, BS_, 2*D_, R_, krb, vtb, cosT, sinT, vsum);

    attn_mfma_k<<<B_*H_*NBLK, 256, 0, stream>>>(qrb, krb, vtb, sel, vsum, attnob);
    gemm_mfma_k<0><<<512, 256, 0, stream>>>(
        attnob, wob, BS_, D_, D_, out, nullptr, nullptr, nullptr, nullptr);
}

// Round 9
// 142.969 us; speedup vs baseline: 1.1840x; 1.0676x over previous
//
#include <hip/hip_runtime.h>
#include <hip/hip_bf16.h>
#include <math.h>

#define B_ 2
#define S_ 2048
#define D_ 1024
#define H_ 16
#define HD_ 64
#define R_ 128
#define NBLK 32
#define TOPK_ 4
#define BS_ (B_*S_)

typedef __attribute__((ext_vector_type(8))) short bf16x8;
typedef __attribute__((ext_vector_type(4))) float f32x4;

__device__ __forceinline__ unsigned short f2bf(float f) {
    unsigned int u = __float_as_uint(f);
    u += 0x7fffu + ((u >> 16) & 1u);
    return (unsigned short)(u >> 16);
}
__device__ __forceinline__ float bf2f(unsigned short h) {
    return __uint_as_float(((unsigned int)h) << 16);
}
__device__ __forceinline__ unsigned int pack2(float a, float b) {
    return (unsigned int)f2bf(a) | ((unsigned int)f2bf(b) << 16);
}
__device__ __forceinline__ void gload_lds16(const void* g, void* l) {
    __builtin_amdgcn_global_load_lds((const __attribute__((address_space(1))) void*)g,
                                     (__attribute__((address_space(3))) void*)l, 16, 0, 0);
}

// ---------------- fused prep: RoPE tables | weight cvt | row-scores + x cvt ----------------
__global__ __launch_bounds__(256) void prep_k(const float* __restrict__ x,
        const float* __restrict__ wsc, const float* __restrict__ wq,
        const float* __restrict__ wkd, const float* __restrict__ wku,
        const float* __restrict__ wo, float* __restrict__ cosT,
        float* __restrict__ sinT, unsigned short* __restrict__ wcat,
        unsigned short* __restrict__ wkub, unsigned short* __restrict__ wob,
        float* __restrict__ rows, unsigned short* __restrict__ xb) {
    const int blk = blockIdx.x;
    if (blk < 512) {                       // RoPE tables
        const int idx = blk*256 + threadIdx.x;
        const int s  = idx >> 6;
        const int hd = idx & 63;
        const int j = (hd < 32) ? hd : hd - 32;
        const float inv = powf(100000.0f, -((float)(2*j) / 64.0f));
        const float fr = (float)s * inv;
        cosT[idx] = cosf(fr);
        sinT[idx] = sinf(fr);
    } else if (blk < 1728) {               // weight converts
        const int wb = blk - 512;
        const float* src; unsigned short* dst; int base;
        if      (wb < 512) { src = wq;  dst = wcat;            base = wb;       }
        else if (wb < 576) { src = wkd; dst = wcat + 1048576;  base = wb - 512; }
        else if (wb < 704) { src = wku; dst = wkub;            base = wb - 576; }
        else               { src = wo;  dst = wob;             base = wb - 704; }
        const int i = base*2048 + threadIdx.x*8;
        float4 a = *(const float4*)&src[i];
        float4 b = *(const float4*)&src[i+4];
        uint4 o;
        o.x = pack2(a.x, a.y); o.y = pack2(a.z, a.w);
        o.z = pack2(b.x, b.y); o.w = pack2(b.z, b.w);
        *(uint4*)&dst[i] = o;
    } else {                               // row scores + x -> bf16
        const int wid  = ((blk - 1728) << 2) + (threadIdx.x >> 6);  // 0..1023
        const int lane = threadIdx.x & 63;
        #pragma unroll
        for (int r = 0; r < 4; ++r) {
            const int row = (wid << 2) + r;                        // 0..4095
            const float* xp = x + (size_t)row * D_;
            unsigned short* xo = xb + (size_t)row * D_;
            float acc = 0.f;
            #pragma unroll
            for (int j = 0; j < 4; ++j) {
                const int off = ((j << 6) + lane) << 2;            // coalesced float4
                float4 xv = *(const float4*)&xp[off];
                float4 wv = *(const float4*)&wsc[off];
                acc = fmaf(xv.x, wv.x, acc);
                acc = fmaf(xv.y, wv.y, acc);
                acc = fmaf(xv.z, wv.z, acc);
                acc = fmaf(xv.w, wv.w, acc);
                uint2 o; o.x = pack2(xv.x, xv.y); o.y = pack2(xv.z, xv.w);
                *(uint2*)&xo[off] = o;
            }
            #pragma unroll
            for (int m = 1; m <= 32; m <<= 1) acc += __shfl_xor(acc, m);
            if (lane == 0) rows[row] = acc;
        }
    }
}

// ---------------- block sums + top-4 (strict > == lowest index on ties); zeroes vsum ----------------
__global__ __launch_bounds__(256) void blocktopk_k(const float* __restrict__ rows,
        int* __restrict__ sel, float* __restrict__ vsum) {
    ((float4*)vsum)[threadIdx.x]       = (float4){0.f,0.f,0.f,0.f};
    ((float4*)vsum)[threadIdx.x + 256] = (float4){0.f,0.f,0.f,0.f};
    __shared__ float bs[64];
    const int bk = threadIdx.x >> 2, qt = threadIdx.x & 3;     // block 0..63, quarter
    const float* rp = rows + (bk << 6) + (qt << 4);
    float p = 0.f;
    #pragma unroll
    for (int i = 0; i < 16; ++i) p += rp[i];
    p += __shfl_xor(p, 1);
    p += __shfl_xor(p, 2);
    if (qt == 0) bs[bk] = p;
    __syncthreads();
    if (threadIdx.x < B_) {
        const int b = threadIdx.x;
        float sc[NBLK];
        for (int i = 0; i < NBLK; ++i) sc[i] = bs[b * NBLK + i];
        for (int j = 0; j < TOPK_; ++j) {
            float best = -INFINITY; int bi = 0;
            for (int i = 0; i < NBLK; ++i)
                if (sc[i] > best) { best = sc[i]; bi = i; }
            sel[b * TOPK_ + j] = bi;
            sc[bi] = -INFINITY;
        }
    }
}

// ---------------- MFMA GEMM C = A @ B^T, 128x64 tile, BK=64, 2-phase dbuf pipeline ----------------
// 1D grid (nwg % 8 == 0), XCD-aware swizzle. EPI 0: fp32 out (o0).
// EPI 1: cols<1024 -> RoPE -> qrb(o0), else latb(o1).
// EPI 2: cols<1024 -> RoPE -> krb(o0), else V -> transposed vtb(o1) + vsum atomics.
template<int EPI>
__global__ __launch_bounds__(256) void gemm_mfma_k(const unsigned short* __restrict__ A,
        const unsigned short* __restrict__ Bm, int M, int N, int K,
        void* __restrict__ o0, void* __restrict__ o1,
        const float* __restrict__ cosT, const float* __restrict__ sinT,
        float* __restrict__ vsum) {
    __shared__ unsigned short shbuf[2][12288];   // per buf: As[8192] | Bs[4096]  (48 KB)
    const int tid  = threadIdx.x;
    const int wave = tid >> 6, lane = tid & 63;
    const int nx = N >> 6;
    const int ob = blockIdx.x;
    const int w  = ((ob & 7) * (gridDim.x >> 3)) + (ob >> 3);
    const int bm = (w / nx) << 7, bn = (w % nx) << 6;
    const int g  = lane >> 4, qc = lane & 15;
    const int srow  = lane >> 3;             // row within 8-row chunk
    const int sslot = (lane & 7) ^ srow;     // inverse-swizzled global 16B slot

    f32x4 acc[2][4];
    #pragma unroll
    for (int m=0;m<2;m++)
        #pragma unroll
        for (int n=0;n<4;n++)
            acc[m][n] = (f32x4){0.f,0.f,0.f,0.f};

    const int NT = K >> 6;
    auto STAGE = [&](int buf, int t) {
        const int k0 = t << 6;
        unsigned short* As = shbuf[buf];
        unsigned short* Bs = shbuf[buf] + 8192;
        #pragma unroll
        for (int it = 0; it < 4; ++it) {
            const int chunk = (it << 2) | wave;       // 0..15
            const int row   = (chunk << 3) | srow;    // 0..127
            gload_lds16(A + (size_t)(bm + row) * K + k0 + (sslot << 3), &As[chunk << 9]);
        }
        #pragma unroll
        for (int it = 0; it < 2; ++it) {
            const int chunk = (it << 2) | wave;       // 0..7
            const int row   = (chunk << 3) | srow;    // 0..63
            gload_lds16(Bm + (size_t)(bn + row) * K + k0 + (sslot << 3), &Bs[chunk << 9]);
        }
    };

    STAGE(0, 0);
    __syncthreads();
    for (int t = 0; t < NT; ++t) {
        if (t + 1 < NT) STAGE((t + 1) & 1, t + 1);    // loads fly under compute
        const unsigned short* As = shbuf[t & 1];
        const unsigned short* Bs = shbuf[t & 1] + 8192;
        #pragma unroll
        for (int ks = 0; ks < 2; ++ks) {
            const int swb = ((ks << 2) | g) ^ (lane & 7);  // swizzled read slot
            bf16x8 af[2], bfr[4];
            #pragma unroll
            for (int m = 0; m < 2; ++m)
                af[m]  = *(const bf16x8*)&As[(((wave << 5) + (m << 4) + qc) << 6) + (swb << 3)];
            #pragma unroll
            for (int n = 0; n < 4; ++n)
                bfr[n] = *(const bf16x8*)&Bs[(((n << 4) + qc) << 6) + (swb << 3)];
            #pragma unroll
            for (int m = 0; m < 2; ++m)
                #pragma unroll
                for (int n = 0; n < 4; ++n)
                    acc[m][n] = __builtin_amdgcn_mfma_f32_16x16x32_bf16(af[m], bfr[n], acc[m][n], 0, 0, 0);
        }
        __syncthreads();
    }

    if (EPI == 0) {
        float* C = (float*)o0;
        #pragma unroll
        for (int m = 0; m < 2; ++m) {
            const int r0 = bm + (wave << 5) + (m << 4) + (g << 2);
            #pragma unroll
            for (int n = 0; n < 4; ++n) {
                const int c = bn + (n << 4) + qc;
                #pragma unroll
                for (int j = 0; j < 4; ++j)
                    C[(size_t)(r0 + j) * N + c] = acc[m][n][j];
            }
        }
    } else {
        const bool isrope = (bn < 1024);
        if (isrope) {
            const int h = bn >> 6;
            unsigned short* dst = (unsigned short*)o0;   // qrb or krb [B,H,S,HD]
            #pragma unroll
            for (int m = 0; m < 2; ++m) {
                const int r0 = bm + (wave << 5) + (m << 4) + (g << 2);
                #pragma unroll
                for (int j = 0; j < 4; ++j) {
                    const int row = r0 + j;
                    const int b = row >> 11, s = row & (S_-1);
                    const size_t obase = ((size_t)(b*H_ + h) * S_ + s) << 6;
                    #pragma unroll
                    for (int n = 0; n < 4; ++n) {
                        const int hd = (n << 4) + qc;
                        const float c_ = cosT[(s << 6) + hd];
                        const float sn = sinT[(s << 6) + hd];
                        const float rot = (n < 2) ? -acc[m][n ^ 2][j] : acc[m][n ^ 2][j];
                        dst[obase + hd] = f2bf(acc[m][n][j] * c_ + rot * sn);
                    }
                }
            }
        } else if (EPI == 1) {         // latent columns 1024..1151
            unsigned short* latb = (unsigned short*)o1;
            const int c0 = bn - 1024;
            #pragma unroll
            for (int m = 0; m < 2; ++m) {
                const int r0 = bm + (wave << 5) + (m << 4) + (g << 2);
                #pragma unroll
                for (int n = 0; n < 4; ++n) {
                    const int c = c0 + (n << 4) + qc;
                    #pragma unroll
                    for (int j = 0; j < 4; ++j)
                        latb[(size_t)(r0 + j) * R_ + c] = f2bf(acc[m][n][j]);
                }
            }
        } else {   // EPI==2 v-cols: LDS-transpose 128x64 tile -> vtb[bh,kb][d][k] + vsum atomics
            const int h  = (bn >> 6) - 16;
            const int b  = bm >> 11, s0 = bm & (S_-1);
            const int bh = (b << 4) + h;
            unsigned short* vtb = (unsigned short*)o1;
            unsigned short (*T)[72] = (unsigned short(*)[72])&shbuf[0][0];   // 18 KB
            #pragma unroll
            for (int m = 0; m < 2; ++m) {
                const int r0 = (wave << 5) + (m << 4) + (g << 2);
                #pragma unroll
                for (int n = 0; n < 4; ++n)
                    #pragma unroll
                    for (int j = 0; j < 4; ++j)
                        T[r0 + j][(n << 4) + qc] = f2bf(acc[m][n][j]);
            }
            __syncthreads();
            #pragma unroll
            for (int u = 0; u < 2; ++u) {            // two 64-key halves
                const int kb = (s0 >> 6) + u;
                unsigned short* dst = vtb + (((size_t)(bh * NBLK + kb)) << 12);
                #pragma unroll
                for (int uu = 0; uu < 2; ++uu) {
                    const int idx = (uu << 8) + tid;     // 0..511
                    const int dd = idx >> 3, k0 = (idx & 7) << 3;
                    unsigned short tmp[8];
                    float sm = 0.f;
                    #pragma unroll
                    for (int j = 0; j < 8; ++j) { tmp[j] = T[(u << 6) + k0 + j][dd]; sm += bf2f(tmp[j]); }
                    *(uint4*)&dst[(size_t)(dd << 6) + k0] = *(uint4*)tmp;
                    sm += __shfl_xor(sm, 1);
                    sm += __shfl_xor(sm, 2);
                    sm += __shfl_xor(sm, 4);
                    if ((tid & 7) == 0) atomicAdd(&vsum[(bh << 6) + dd], sm);
                }
            }
        }
    }
}

// ---------------- MFMA block-sparse attention: 4 waves x 16 q-rows; gload_lds + XOR-swz staging ----------------
__global__ __launch_bounds__(256) void attn_mfma_k(const unsigned short* __restrict__ qrb,
        const unsigned short* __restrict__ krb, const unsigned short* __restrict__ vtb,
        const int* __restrict__ sel, const float* __restrict__ vsum,
        unsigned short* __restrict__ attno) {
    const int qb = blockIdx.x & (NBLK-1);
    const int bh = blockIdx.x >> 5;
    const int b  = bh >> 4;
    const int h  = bh & 15;
    const int tid  = threadIdx.x;
    const int wave = tid >> 6, lane = tid & 63;
    const int g = lane >> 4, qc = lane & 15;

    __shared__ unsigned short Ks[64*64];       // linear [key][d], XOR-swz slots
    __shared__ unsigned short Vt[64*64];       // linear [d][key], XOR-swz slots
    __shared__ unsigned short Pl[4][16][72];   // per-wave P [q][key], padded
    __shared__ float cfl[4][16];
    __shared__ float lvl[4][16];

    int selb[4];
    #pragma unroll
    for (int j=0;j<4;j++) selb[j] = sel[(b<<2)+j];
    const bool diag = (selb[0]==qb)|(selb[1]==qb)|(selb[2]==qb)|(selb[3]==qb);

    // build wg-uniform block list (selected < qb, then diagonal)
    int kbl[5]; int cnt = 0;
    #pragma unroll
    for (int j=0;j<4;j++) if (selb[j] < qb) kbl[cnt++] = selb[j];
    const int dstart = cnt;
    if (diag) kbl[cnt++] = qb;

    // Q B-frags (per wave: rows qb*64 + wave*16 .. +16)
    const unsigned short* qp = qrb + (((size_t)bh*S_ + (qb<<6) + (wave<<4) + qc) << 6);
    bf16x8 bq[2];
    bq[0] = *(const bf16x8*)(qp + (g<<3));
    bq[1] = *(const bf16x8*)(qp + 32 + (g<<3));

    f32x4 oacc[4];
    #pragma unroll
    for (int n=0;n<4;n++) oacc[n] = (f32x4){0.f,0.f,0.f,0.f};
    float mrun = -INFINITY, lrun = 0.f;
    const int qib = (wave<<4) + qc;   // this lane's q-row within the 64-block

    const int srow = lane >> 3;                    // 0..7 within 8-row chunk
    const int sslot = (lane & 7) ^ srow;           // inverse-swizzled 16B slot

    for (int i = 0; i < cnt; ++i) {
        const int kb = kbl[i];
        const bool isdiag = (i >= dstart);
        const unsigned short* kB = krb + (((size_t)bh*S_ + (kb<<6)) << 6);
        const unsigned short* vT = vtb + (((size_t)(bh*NBLK + kb)) << 12);
        __syncthreads();
        #pragma unroll
        for (int it = 0; it < 2; ++it) {
            const int chunk = (it << 2) | wave;    // 0..7, 8 rows each
            const int row = (chunk << 3) | srow;
            gload_lds16(kB + (row << 6) + (sslot << 3), &Ks[chunk << 9]);
            gload_lds16(vT + (row << 6) + (sslot << 3), &Vt[chunk << 9]);
        }
        __syncthreads();

        // S^T = K @ Q^T : lane holds q-col=qc, keys 16m+4g+{0..3}
        f32x4 sf[4];
        #pragma unroll
        for (int m=0;m<4;m++) sf[m] = (f32x4){0.f,0.f,0.f,0.f};
        #pragma unroll
        for (int ks=0;ks<2;ks++)
            #pragma unroll
            for (int m=0;m<4;m++) {
                const int sw = (((ks<<2)|g) ^ (qc & 7)) << 3;
                bf16x8 ak = *(const bf16x8*)&Ks[(((m<<4)+qc)<<6) + sw];
                sf[m] = __builtin_amdgcn_mfma_f32_16x16x32_bf16(ak, bq[ks], sf[m], 0, 0, 0);
            }

        float s[16];
        float bmax = -INFINITY;
        #pragma unroll
        for (int m=0;m<4;m++)
            #pragma unroll
            for (int r2=0;r2<4;r2++) {
                const int kl = (m<<4)+(g<<2)+r2;
                float v = sf[m][r2]*0.125f;
                if (isdiag && kl > qib) v = -1e30f;
                s[(m<<2)+r2] = v;
                bmax = fmaxf(bmax, v);
            }
        bmax = fmaxf(bmax, __shfl_xor(bmax, 16));
        bmax = fmaxf(bmax, __shfl_xor(bmax, 32));
        const float mnew = fmaxf(mrun, bmax);
        const float cf = __expf(mrun - mnew);
        float ls = 0.f;
        #pragma unroll
        for (int m=0;m<4;m++) {
            float p0 = __expf(s[(m<<2)+0]-mnew);
            float p1 = __expf(s[(m<<2)+1]-mnew);
            float p2 = __expf(s[(m<<2)+2]-mnew);
            float p3 = __expf(s[(m<<2)+3]-mnew);
            ls += p0+p1+p2+p3;
            const int koff = (m<<4)+(g<<2);
            *(unsigned int*)&Pl[wave][qc][koff]   = pack2(p0,p1);
            *(unsigned int*)&Pl[wave][qc][koff+2] = pack2(p2,p3);
        }
        ls += __shfl_xor(ls, 16);
        ls += __shfl_xor(ls, 32);
        lrun = lrun*cf + ls;
        cfl[wave][qc] = cf;
        f32x4 cf4 = *(const f32x4*)&cfl[wave][g<<2];
        #pragma unroll
        for (int n=0;n<4;n++) oacc[n] *= cf4;
        // O += P @ V  (A = P from per-wave LDS, B = Vt rows from swizzled LDS)
        #pragma unroll
        for (int ks=0;ks<2;ks++) {
            bf16x8 pa = *(const bf16x8*)&Pl[wave][qc][(ks<<5)+(g<<3)];
            #pragma unroll
            for (int n=0;n<4;n++) {
                const int sw = (((ks<<2)|g) ^ (qc & 7)) << 3;
                bf16x8 vb = *(const bf16x8*)&Vt[(((n<<4)+qc)<<6) + sw];
                oacc[n] = __builtin_amdgcn_mfma_f32_16x16x32_bf16(pa, vb, oacc[n], 0, 0, 0);
            }
        }
        mrun = mnew;
    }

    f32x4 il4 = (f32x4){0.f,0.f,0.f,0.f};
    if (cnt) {
        lvl[wave][qc] = 1.0f / lrun;
        il4 = *(const f32x4*)&lvl[wave][g<<2];
    }
    #pragma unroll
    for (int n=0;n<4;n++)
        #pragma unroll
        for (int r2=0;r2<4;r2++) {
            float val = cnt ? oacc[n][r2]*il4[r2]
                            : vsum[(bh<<6)+(n<<4)+qc] * (1.0f/(float)S_);
            const int row = (qb<<6) + (wave<<4) + (g<<2) + r2;
            attno[(((size_t)(b*S_+row))<<10) + (h<<6) + (n<<4) + qc] = f2bf(val);
        }
}

extern "C" void kernel_launch(void* const* d_in, const int* in_sizes, int n_in,
                              void* d_out, int out_size, void* d_ws, size_t ws_size,
                              hipStream_t stream) {
    (void)in_sizes; (void)n_in; (void)out_size; (void)ws_size;
    const float* x     = (const float*)d_in[0];
    const float* w_q   = (const float*)d_in[1];
    const float* w_kvd = (const float*)d_in[2];
    const float* w_kvu = (const float*)d_in[3];
    const float* w_o   = (const float*)d_in[4];
    const float* w_sc  = (const float*)d_in[5];
    float* out = (float*)d_out;

    char* p = (char*)d_ws;
    auto alloc = [&](size_t bytes) -> void* {
        void* r = (void*)p;
        p += (bytes + 255) & ~(size_t)255;
        return r;
    };
    float* cosT  = (float*)alloc((size_t)S_*HD_*4);
    float* sinT  = (float*)alloc((size_t)S_*HD_*4);
    unsigned short* xb    = (unsigned short*)alloc((size_t)BS_*D_*2);
    unsigned short* wcat  = (unsigned short*)alloc((size_t)(D_+R_)*D_*2);   // w_q ; w_kvd
    unsigned short* wkub  = (unsigned short*)alloc((size_t)2*D_*R_*2);
    unsigned short* wob   = (unsigned short*)alloc((size_t)D_*D_*2);
    unsigned short* latb  = (unsigned short*)alloc((size_t)BS_*R_*2);
    unsigned short* qrb   = (unsigned short*)alloc((size_t)BS_*D_*2);
    unsigned short* krb   = (unsigned short*)alloc((size_t)BS_*D_*2);
    unsigned short* vtb   = (unsigned short*)alloc((size_t)BS_*D_*2);
    unsigned short* attnob= (unsigned short*)alloc((size_t)BS_*D_*2);
    float* rows   = (float*)alloc((size_t)BS_*4);
    int*   sel    = (int*)  alloc((size_t)B_*TOPK_*4);
    float* vsum   = (float*)alloc((size_t)B_*H_*HD_*4);

    prep_k<<<1984, 256, 0, stream>>>(x, w_sc, w_q, w_kvd, w_kvu, w_o,
                                     cosT, sinT, wcat, wkub, wob, rows, xb);
    blocktopk_k<<<1, 256, 0, stream>>>(rows, sel, vsum);

    // q-proj + kv-down fused (N = 1024 + 128), RoPE'd q -> qrb, latent -> latb
    gemm_mfma_k<1><<<576, 256, 0, stream>>>(
        xb, wcat, BS_, D_+R_, D_, qrb, latb, cosT, sinT, nullptr);
    // kv-up: RoPE'd k -> krb, v -> transposed vtb (+vsum)
    gemm_mfma_k<2><<<1024, 256, 0, stream>>>(
        latb, wkub, BS_, 2*D_, R_, krb, vtb, cosT, sinT, vsum);

    attn_mfma_k<<<B_*H_*NBLK, 256, 0, stream>>>(qrb, krb, vtb, sel, vsum, attnob);
    gemm_mfma_k<0><<<512, 256, 0, stream>>>(
        attnob, wob, BS_, D_, D_, out, nullptr, nullptr, nullptr, nullptr);
}